// Round 8
// baseline (143.494 us; speedup 1.0000x reference)
//
#include <hip/hip_runtime.h>
#include <hip/hip_cooperative_groups.h>
#include <hip/hip_bf16.h>

namespace cg = cooperative_groups;

#define NROWS 8192
#define DDIM  128
#define KTOT  256                   // rows of Gt (a-dim): [Qn cols | Kn cols]
#define GT_ROWB (NROWS * 2)         // bytes per Gt row = 16384
#define NKCH  64                    // K-chunks over N
#define CHN   (NROWS / NKCH)        // 128 n-rows per chunk (256 B)
#define NPAIR 10                    // triangular (ti<=tj) over 4 a-groups
#define NUNITS (NPAIR * NKCH)       // 640
#define GRID  160
#define LDSPAD 260                  // norm LDS row stride in shorts

typedef unsigned short ushort_t;
typedef unsigned int   uint_t;
typedef __attribute__((ext_vector_type(8))) short short8;
typedef __attribute__((ext_vector_type(4))) float floatx4;

#define LDS_PTR(p) ((__attribute__((address_space(3))) void*)(p))
#define GLB_PTR(p) ((const __attribute__((address_space(1))) void*)(p))

// round-to-nearest-even fp32 -> bf16 bits
static __device__ inline ushort_t f2bf(float f) {
    union { float f; uint_t u; } a; a.f = f;
    uint_t u = a.u + 0x7fffu + ((a.u >> 16) & 1u);
    return (ushort_t)(u >> 16);
}

// decode triangular pair p -> (ti,tj), ti<=tj over 4 groups
static __device__ inline void pair_decode(int p, int* ti, int* tj) {
    int i = 0, len = 4;
    while (p >= len) { p -= len; len--; i++; }
    *ti = i; *tj = i + p;
}

// ONE cooperative kernel: norm+transpose -> partial Grams (atomic S) -> reduce.
// Grid 160 x 256, 64 KB LDS (2 blocks/CU co-resident; capacity 512 >= 160).
__global__ __launch_bounds__(256) void fused_kernel(
    const float* __restrict__ q, const float* __restrict__ k,
    ushort_t* __restrict__ Gt, float* __restrict__ S,
    double* acc, float* out)
{
    __shared__ ushort_t lds[32768];   // 64 KB, repurposed per phase
    cg::grid_group grid = cg::this_grid();

    int tid = threadIdx.x;
    int bid = blockIdx.x;

    // ================= Phase A: normalize + transpose =================
    if (bid < 128) {
        // 64 n-rows per block (R7 norm_t structure)
        int w  = tid >> 6;
        int l  = tid & 63;
        int h  = l >> 5;          // half-wave: row parity
        int li = l & 31;          // lane within half: 4 floats each

        #pragma unroll
        for (int i = 0; i < 8; ++i) {
            int rl  = w * 16 + 2 * i + h;            // local n-row 0..63
            int row = bid * 64 + rl;
            {
                float4 v = ((const float4*)(q + (size_t)row * DDIM))[li];
                float ss = v.x * v.x + v.y * v.y + v.z * v.z + v.w * v.w;
                #pragma unroll
                for (int o = 16; o > 0; o >>= 1) ss += __shfl_xor(ss, o, 64);
                float inv = rsqrtf(fmaxf(ss, 1e-16f));
                uint2 p2;
                p2.x = (uint_t)f2bf(v.x * inv) | ((uint_t)f2bf(v.y * inv) << 16);
                p2.y = (uint_t)f2bf(v.z * inv) | ((uint_t)f2bf(v.w * inv) << 16);
                *(uint2*)&lds[rl * LDSPAD + 4 * li] = p2;
            }
            {
                float4 v = ((const float4*)(k + (size_t)row * DDIM))[li];
                float ss = v.x * v.x + v.y * v.y + v.z * v.z + v.w * v.w;
                #pragma unroll
                for (int o = 16; o > 0; o >>= 1) ss += __shfl_xor(ss, o, 64);
                float inv = rsqrtf(fmaxf(ss, 1e-16f));
                uint2 p2;
                p2.x = (uint_t)f2bf(v.x * inv) | ((uint_t)f2bf(v.y * inv) << 16);
                p2.y = (uint_t)f2bf(v.z * inv) | ((uint_t)f2bf(v.w * inv) << 16);
                *(uint2*)&lds[rl * LDSPAD + 128 + 4 * li] = p2;
            }
        }
        __syncthreads();

        // thread owns Gt row a=tid; gather 64 shorts from LDS column a
        int a = tid;
        char* gdst = (char*)Gt + (size_t)a * GT_ROWB + (size_t)bid * 128;
        #pragma unroll
        for (int g = 0; g < 8; ++g) {
            union { ushort_t u16[8]; uint4 v; } tmp;
            #pragma unroll
            for (int e = 0; e < 8; ++e)
                tmp.u16[e] = lds[(g * 8 + e) * LDSPAD + a];
            *(uint4*)(gdst + g * 16) = tmp.v;
        }
    } else {
        // blocks 128..159: zero S (40960 floats = 32*256*5) + scalars
        int base = (bid - 128) * 1280 + tid;
        #pragma unroll
        for (int j = 0; j < 5; ++j)
            S[base + j * 256] = 0.f;
        if (bid == 128 && tid == 0) *acc = 0.0;
    }
    grid.sync();

    // ================= Phase B: partial Grams via MFMA, atomic into S ======
    {
        int half   = tid >> 7;            // sub-block 0/1 within block
        int t128   = tid & 127;
        int sbase  = half * 16384;        // shorts: 32 KB per sub-block
        ushort_t* sA = &lds[sbase];
        ushort_t* sB = &lds[sbase + 8192];

        int w    = t128 >> 6;             // a-strip
        int l    = tid & 63;
        int m    = l & 15;
        int quad = l >> 4;

        int sb = bid * 2 + half;          // sub-block id 0..319
        #pragma unroll
        for (int rep = 0; rep < 2; ++rep) {
            int u    = sb + rep * 320;    // unit 0..639, perfectly balanced
            int pair = u >> 6;
            int c    = u & 63;
            int ti, tj;
            pair_decode(pair, &ti, &tj);

            const char* gA = (const char*)Gt + (size_t)(ti * 64) * GT_ROWB + c * (CHN * 2);
            const char* gB = (const char*)Gt + (size_t)(tj * 64) * GT_ROWB + c * (CHN * 2);

            // stage both 64x128 panels: 1024 16B-chunks each, 8 iters/thread
            #pragma unroll
            for (int it = 0; it < 8; ++it) {
                int ch = it * 128 + t128;
                int row = ch >> 4, phys = ch & 15;
                int logical = phys ^ (row & 7);
                __builtin_amdgcn_global_load_lds(GLB_PTR(gA + (size_t)row * GT_ROWB + logical * 16),
                                                 LDS_PTR((char*)sA + ch * 16), 16, 0, 0);
            }
            #pragma unroll
            for (int it = 0; it < 8; ++it) {
                int ch = it * 128 + t128;
                int row = ch >> 4, phys = ch & 15;
                int logical = phys ^ (row & 7);
                __builtin_amdgcn_global_load_lds(GLB_PTR(gB + (size_t)row * GT_ROWB + logical * 16),
                                                 LDS_PTR((char*)sB + ch * 16), 16, 0, 0);
            }
            __syncthreads();

            floatx4 accC[2][4];
            #pragma unroll
            for (int at = 0; at < 2; ++at)
                #pragma unroll
                for (int bt = 0; bt < 4; ++bt)
                    accC[at][bt] = (floatx4){0.f, 0.f, 0.f, 0.f};

            #pragma unroll
            for (int kp = 0; kp < 4; ++kp) {
                short8 af[2], bf[4];
                #pragma unroll
                for (int at = 0; at < 2; ++at) {
                    int ra   = w * 32 + at * 16 + m;
                    int phys = (kp * 4 + quad) ^ (ra & 7);
                    af[at] = *(const short8*)&sA[ra * CHN + phys * 8];
                }
                #pragma unroll
                for (int bt = 0; bt < 4; ++bt) {
                    int rb   = bt * 16 + m;
                    int phys = (kp * 4 + quad) ^ (rb & 7);
                    bf[bt] = *(const short8*)&sB[rb * CHN + phys * 8];
                }
                #pragma unroll
                for (int at = 0; at < 2; ++at)
                    #pragma unroll
                    for (int bt = 0; bt < 4; ++bt)
                        accC[at][bt] = __builtin_amdgcn_mfma_f32_16x16x32_bf16(af[at], bf[bt], accC[at][bt], 0, 0, 0);
            }

            // atomic-accumulate 64x64 partial into S[pair]
            float* st = S + pair * 4096;
            #pragma unroll
            for (int at = 0; at < 2; ++at)
                #pragma unroll
                for (int bt = 0; bt < 4; ++bt)
                    #pragma unroll
                    for (int r = 0; r < 4; ++r) {
                        int row = w * 32 + at * 16 + quad * 4 + r;
                        int col = bt * 16 + m;
                        atomicAdd(&st[row * 64 + col], accC[at][bt][r]);
                    }
            __syncthreads();   // LDS reuse guard; equal count across halves
        }
    }
    grid.sync();

    // ================= Phase C: weight, square, reduce =================
    {
        __shared__ float wsum[4];
        int e    = bid * 256 + tid;     // 0..40959 (= 160*256 exactly)
        int pair = e >> 12;
        int idx  = e & 4095;

        float s = S[(size_t)pair * 4096 + idx];
        int ti, tj;
        pair_decode(pair, &ti, &tj);
        float wgt = ((ti < 2) == (tj < 2)) ? 1.f : -1.f;
        if (ti != tj) wgt *= 2.f;
        float v = wgt * s * s;

        int w = tid >> 6, l = tid & 63;
        #pragma unroll
        for (int o = 32; o > 0; o >>= 1) v += __shfl_xor(v, o, 64);
        if (l == 0) wsum[w] = v;
        __syncthreads();
        if (tid == 0) {
            double t = (double)wsum[0] + (double)wsum[1] + (double)wsum[2] + (double)wsum[3];
            atomicAdd(acc, t);
        }
    }
    grid.sync();

    if (bid == 0 && tid == 0) {
        double total = atomicAdd(acc, 0.0);   // coherent device-scope read
        out[0] = (float)(total * (1.0 / ((double)NROWS * (double)(NROWS - 1))));
    }
}

extern "C" void kernel_launch(void* const* d_in, const int* in_sizes, int n_in,
                              void* d_out, int out_size, void* d_ws, size_t ws_size,
                              hipStream_t stream) {
    const float* q = (const float*)d_in[0];
    const float* k = (const float*)d_in[1];
    float* out = (float*)d_out;

    double*   acc = (double*)d_ws;
    ushort_t* Gt  = (ushort_t*)((char*)d_ws + 256);                        // 4 MB
    float*    S   = (float*)((char*)d_ws + 256 + (size_t)KTOT * GT_ROWB);  // 160 KB

    void* args[] = { (void*)&q, (void*)&k, (void*)&Gt, (void*)&S, (void*)&acc, (void*)&out };
    hipLaunchCooperativeKernel((const void*)fused_kernel, dim3(GRID), dim3(256),
                               args, 0, stream);
}

// Round 9
// 80.309 us; speedup vs baseline: 1.7868x; 1.7868x over previous
//
#include <hip/hip_runtime.h>
#include <hip/hip_bf16.h>

#define NROWS 8192
#define DDIM  128
#define KTOT  256                   // rows of Gt (a-dim): [Qn cols | Kn cols]
#define GT_ROWB (NROWS * 2)         // bytes per Gt row = 16384
#define NKCH  64                    // K-chunks over N
#define CHN   (NROWS / NKCH)        // 128 n-rows per chunk
#define NPAIR 10                    // triangular (ti<=tj) over 4 a-groups
#define GB_BLOCKS 320               // gram_b grid (10*4096*2/256)
#define LDSPAD 260                  // norm LDS row stride in shorts

typedef unsigned short ushort_t;
typedef unsigned int   uint_t;
typedef __attribute__((ext_vector_type(8))) short short8;
typedef __attribute__((ext_vector_type(4))) float floatx4;

#define LDS_PTR(p) ((__attribute__((address_space(3))) void*)(p))
#define GLB_PTR(p) ((const __attribute__((address_space(1))) void*)(p))

// round-to-nearest-even fp32 -> bf16 bits
static __device__ inline ushort_t f2bf(float f) {
    union { float f; uint_t u; } a; a.f = f;
    uint_t u = a.u + 0x7fffu + ((a.u >> 16) & 1u);
    return (ushort_t)(u >> 16);
}

// decode triangular pair p -> (ti,tj), ti<=tj over 4 groups
static __device__ inline void pair_decode(int p, int* ti, int* tj) {
    int i = 0, len = 4;
    while (p >= len) { p -= len; len--; i++; }
    *ti = i; *tj = i + p;
}

// K1: row-normalize q,k -> bf16, write TRANSPOSED Gt (256 x 8192).
// 256 blocks x 32 rows (2x parallelism vs R7). Zeroes acc + counter.
__global__ __launch_bounds__(256) void norm_t_kernel(
    const float* __restrict__ q, const float* __restrict__ k,
    ushort_t* __restrict__ Gt, double* acc, uint_t* counter)
{
    __shared__ ushort_t lds[32 * LDSPAD];   // 16.6 KB
    if (blockIdx.x == 0 && threadIdx.x == 0) { *acc = 0.0; *counter = 0u; }
    int w  = threadIdx.x >> 6;
    int l  = threadIdx.x & 63;
    int h  = l >> 5;          // half-wave: row parity
    int li = l & 31;          // lane within half: 4 floats each

    #pragma unroll
    for (int i = 0; i < 4; ++i) {
        int rl  = w * 8 + 2 * i + h;             // local n-row 0..31
        int row = blockIdx.x * 32 + rl;
        {
            float4 v = ((const float4*)(q + (size_t)row * DDIM))[li];
            float ss = v.x * v.x + v.y * v.y + v.z * v.z + v.w * v.w;
            #pragma unroll
            for (int o = 16; o > 0; o >>= 1) ss += __shfl_xor(ss, o, 64);
            float inv = rsqrtf(fmaxf(ss, 1e-16f));
            uint2 p2;
            p2.x = (uint_t)f2bf(v.x * inv) | ((uint_t)f2bf(v.y * inv) << 16);
            p2.y = (uint_t)f2bf(v.z * inv) | ((uint_t)f2bf(v.w * inv) << 16);
            *(uint2*)&lds[rl * LDSPAD + 4 * li] = p2;           // cols 4li..4li+3
        }
        {
            float4 v = ((const float4*)(k + (size_t)row * DDIM))[li];
            float ss = v.x * v.x + v.y * v.y + v.z * v.z + v.w * v.w;
            #pragma unroll
            for (int o = 16; o > 0; o >>= 1) ss += __shfl_xor(ss, o, 64);
            float inv = rsqrtf(fmaxf(ss, 1e-16f));
            uint2 p2;
            p2.x = (uint_t)f2bf(v.x * inv) | ((uint_t)f2bf(v.y * inv) << 16);
            p2.y = (uint_t)f2bf(v.z * inv) | ((uint_t)f2bf(v.w * inv) << 16);
            *(uint2*)&lds[rl * LDSPAD + 128 + 4 * li] = p2;     // cols 128+4li..
        }
    }
    __syncthreads();

    // phase 2: thread owns Gt row a=tid; gather 32 shorts from LDS column a
    int a = threadIdx.x;
    char* gdst = (char*)Gt + (size_t)a * GT_ROWB + (size_t)blockIdx.x * 64;
    #pragma unroll
    for (int g = 0; g < 4; ++g) {
        union { ushort_t u16[8]; uint4 v; } tmp;
        #pragma unroll
        for (int e = 0; e < 8; ++e)
            tmp.u16[e] = lds[(g * 8 + e) * LDSPAD + a];
        *(uint4*)(gdst + g * 16) = tmp.v;
    }
}

// K2: partial Gram (unchanged from R7-verified). 10 symmetric tiles x 64
// K-chunks = 640 blocks, 128 threads, 32 KB LDS. global_load_lds staging with
// XOR-chunk swizzle; MFMA 16x16x32 bf16; fp32 partial tiles to P.
__global__ __launch_bounds__(128, 2) void gram_a_kernel(
    const ushort_t* __restrict__ Gt, float* __restrict__ P)
{
    __shared__ ushort_t sA[64 * CHN];   // 16 KB
    __shared__ ushort_t sB[64 * CHN];   // 16 KB

    int pair = blockIdx.x >> 6;         // 0..9
    int c    = blockIdx.x & 63;         // k-chunk
    int ti, tj;
    pair_decode(pair, &ti, &tj);
    int tid = threadIdx.x;

    const char* gA = (const char*)Gt + (size_t)(ti * 64) * GT_ROWB + c * (CHN * 2);
    const char* gB = (const char*)Gt + (size_t)(tj * 64) * GT_ROWB + c * (CHN * 2);

    #pragma unroll
    for (int it = 0; it < 8; ++it) {
        int ch = it * 128 + tid;               // 0..1023
        int row = ch >> 4, phys = ch & 15;
        int logical = phys ^ (row & 7);
        __builtin_amdgcn_global_load_lds(GLB_PTR(gA + (size_t)row * GT_ROWB + logical * 16),
                                         LDS_PTR((char*)sA + ch * 16), 16, 0, 0);
    }
    #pragma unroll
    for (int it = 0; it < 8; ++it) {
        int ch = it * 128 + tid;
        int row = ch >> 4, phys = ch & 15;
        int logical = phys ^ (row & 7);
        __builtin_amdgcn_global_load_lds(GLB_PTR(gB + (size_t)row * GT_ROWB + logical * 16),
                                         LDS_PTR((char*)sB + ch * 16), 16, 0, 0);
    }
    __syncthreads();

    int w    = tid >> 6;        // a-strip: rows w*32..w*32+31
    int l    = tid & 63;
    int m    = l & 15;
    int quad = l >> 4;

    floatx4 accC[2][4];
    #pragma unroll
    for (int at = 0; at < 2; ++at)
        #pragma unroll
        for (int bt = 0; bt < 4; ++bt)
            accC[at][bt] = (floatx4){0.f, 0.f, 0.f, 0.f};

    #pragma unroll
    for (int kp = 0; kp < 4; ++kp) {
        short8 af[2], bf[4];
        #pragma unroll
        for (int at = 0; at < 2; ++at) {
            int ra   = w * 32 + at * 16 + m;
            int phys = (kp * 4 + quad) ^ (ra & 7);
            af[at] = *(const short8*)&sA[ra * CHN + phys * 8];
        }
        #pragma unroll
        for (int bt = 0; bt < 4; ++bt) {
            int rb   = bt * 16 + m;
            int phys = (kp * 4 + quad) ^ (rb & 7);
            bf[bt] = *(const short8*)&sB[rb * CHN + phys * 8];
        }
        #pragma unroll
        for (int at = 0; at < 2; ++at)
            #pragma unroll
            for (int bt = 0; bt < 4; ++bt)
                accC[at][bt] = __builtin_amdgcn_mfma_f32_16x16x32_bf16(af[at], bf[bt], accC[at][bt], 0, 0, 0);
    }

    // write 64x64 fp32 partial (C layout: col=m, row=quad*4+reg)
    float* pt = P + ((size_t)pair * NKCH + c) * 4096;
    #pragma unroll
    for (int at = 0; at < 2; ++at)
        #pragma unroll
        for (int bt = 0; bt < 4; ++bt)
            #pragma unroll
            for (int r = 0; r < 4; ++r) {
                int row = w * 32 + at * 16 + quad * 4 + r;
                int col = bt * 16 + m;
                pt[row * 64 + col] = accC[at][bt][r];
            }
}

// K3: reduce partials (lane-pairs split the 64 chunks: 32 loads each), weight,
// square, fp64 accumulate; LAST block finalizes into out.
__global__ __launch_bounds__(256) void gram_b_kernel(
    const float* __restrict__ P, double* acc, uint_t* counter, float* out)
{
    __shared__ float wsum[4];
    int tid  = threadIdx.x;
    int e    = blockIdx.x * 128 + (tid >> 1);    // element 0..40959 (pair uniform/block)
    int par  = tid & 1;
    int pair = e >> 12;
    int idx  = e & 4095;

    const float* base = P + ((size_t)pair * NKCH + par * 32) * 4096 + idx;
    float s = 0.f;
    #pragma unroll
    for (int c = 0; c < 32; ++c)
        s += base[(size_t)c * 4096];
    s += __shfl_xor(s, 1, 64);                   // full 64-chunk sum, both lanes

    int ti, tj;
    pair_decode(pair, &ti, &tj);
    float wgt = ((ti < 2) == (tj < 2)) ? 1.f : -1.f;
    if (ti != tj) wgt *= 2.f;                    // symmetric tile counted twice
    float v = (par == 0) ? wgt * s * s : 0.f;    // count each element once

    int w = tid >> 6, l = tid & 63;
    #pragma unroll
    for (int o = 32; o > 0; o >>= 1) v += __shfl_xor(v, o, 64);
    if (l == 0) wsum[w] = v;
    __syncthreads();
    if (tid == 0) {
        double t = (double)wsum[0] + (double)wsum[1] + (double)wsum[2] + (double)wsum[3];
        atomicAdd(acc, t);
        __threadfence();
        uint_t old = atomicAdd(counter, 1u);
        if (old == GB_BLOCKS - 1) {
            double total = atomicAdd(acc, 0.0);  // coherent read of final sum
            out[0] = (float)(total * (1.0 / ((double)NROWS * (double)(NROWS - 1))));
        }
    }
}

extern "C" void kernel_launch(void* const* d_in, const int* in_sizes, int n_in,
                              void* d_out, int out_size, void* d_ws, size_t ws_size,
                              hipStream_t stream) {
    const float* q = (const float*)d_in[0];
    const float* k = (const float*)d_in[1];
    float* out = (float*)d_out;

    double*   acc = (double*)d_ws;
    uint_t*   cnt = (uint_t*)((char*)d_ws + 64);
    ushort_t* Gt  = (ushort_t*)((char*)d_ws + 256);                        // 4 MB
    float*    P   = (float*)((char*)d_ws + 256 + (size_t)KTOT * GT_ROWB);  // 10 MB

    norm_t_kernel<<<NROWS / 32, 256, 0, stream>>>(q, k, Gt, acc, cnt);
    gram_a_kernel<<<NPAIR * NKCH, 128, 0, stream>>>(Gt, P);
    gram_b_kernel<<<GB_BLOCKS, 256, 0, stream>>>(P, acc, cnt, out);
}